// Round 1
// baseline (186.334 us; speedup 1.0000x reference)
//
#include <hip/hip_runtime.h>
#include <hip/hip_bf16.h>

// MaskedSelfAttention: B=2, S=2048, D=1024, H=16, depth=64.
// Pipeline: convert/transpose -> fused QKV GEMM (bf16 MFMA) -> flash attn
// (anti-causal mask: valid keys k>q; last row = uniform mean(V)) -> out GEMM.

using bf16   = __bf16;
using bf16x4 = __attribute__((ext_vector_type(4))) __bf16;
using bf16x8 = __attribute__((ext_vector_type(8))) __bf16;
using f32x4  = __attribute__((ext_vector_type(4))) float;

__device__ __forceinline__ void load_lds16(const void* g, void* l) {
  __builtin_amdgcn_global_load_lds(
      (const __attribute__((address_space(1))) void*)g,
      (__attribute__((address_space(3))) void*)l, 16, 0, 0);
}

// ---------------- convert x (f32 -> bf16) ----------------
__global__ __launch_bounds__(256) void convert_x(const float* __restrict__ x,
                                                 bf16* __restrict__ xb) {
  const int i = (blockIdx.x * 256 + threadIdx.x) * 4;
  const float4 v = *(const float4*)(x + i);
  bf16x4 o;
  o[0] = (bf16)v.x; o[1] = (bf16)v.y; o[2] = (bf16)v.z; o[3] = (bf16)v.w;
  *(bf16x4*)(xb + i) = o;
}

// ---------------- transpose weight [1024][1024] f32 -> [n][k] bf16 ----------------
__global__ __launch_bounds__(256) void transpose_w(const float* __restrict__ w,
                                                   bf16* __restrict__ out) {
  __shared__ float tile[64][65];
  const int t  = threadIdx.x;
  const int n0 = (blockIdx.x & 15) * 64;
  const int k0 = (blockIdx.x >> 4) * 64;
#pragma unroll
  for (int p = 0; p < 4; ++p) {
    const int row = p * 16 + (t >> 4);
    const int c4  = (t & 15) * 4;
    const float4 v = *(const float4*)&w[(size_t)(k0 + row) * 1024 + n0 + c4];
    tile[row][c4 + 0] = v.x; tile[row][c4 + 1] = v.y;
    tile[row][c4 + 2] = v.z; tile[row][c4 + 3] = v.w;
  }
  __syncthreads();
#pragma unroll
  for (int p = 0; p < 4; ++p) {
    const int rn = p * 16 + (t >> 4);
    const int c4 = (t & 15) * 4;
    bf16x4 o;
#pragma unroll
    for (int j = 0; j < 4; ++j) o[j] = (bf16)tile[c4 + j][rn];
    *(bf16x4*)&out[(size_t)(n0 + rn) * 1024 + k0 + c4] = o;
  }
}

// ---------------- GEMM C = A[M][1024] * Bt[N][1024]^T ----------------
// MODE 0: N=3072 fused QKV epilogue (scatter Q,K flat; V transposed) + biases
// MODE 1: N=1024 output epilogue: f32 out + bias
template <int MODE>
__global__ __launch_bounds__(256, 2) void gemm_bt(
    const bf16* __restrict__ A, const bf16* __restrict__ Bt,
    const float* __restrict__ bias0, const float* __restrict__ bias1,
    const float* __restrict__ bias2, bf16* __restrict__ qf,
    bf16* __restrict__ kf, bf16* __restrict__ vt, float* __restrict__ fout,
    int Nblocks) {
  __shared__ __align__(16) char smem[32768];
  char* sA = smem;
  char* sB = smem + 16384;
  const int tid = threadIdx.x;
  const int lane = tid & 63;
  const int w = tid >> 6;
  const int wm = w >> 1, wn = w & 1;
  const int bid = blockIdx.x;
  const int m0 = (bid / Nblocks) * 128;
  const int n0 = (bid % Nblocks) * 128;

  const char* Ab = (const char*)A;
  const char* Bb = (const char*)Bt;
  size_t srcA[4], srcB[4];
#pragma unroll
  for (int it = 0; it < 4; ++it) {
    const int o = it * 4096 + tid * 16;
    const int r = o >> 7;
    const int cg = ((o >> 4) & 7) ^ (r & 7);
    srcA[it] = (size_t)(m0 + r) * 2048 + cg * 16;
    srcB[it] = (size_t)(n0 + r) * 2048 + cg * 16;
  }

  f32x4 acc[4][4] = {};

  for (int kt = 0; kt < 16; ++kt) {
    const size_t kb = (size_t)kt * 128;
#pragma unroll
    for (int it = 0; it < 4; ++it) {
      load_lds16(Ab + srcA[it] + kb, sA + it * 4096 + w * 1024);
      load_lds16(Bb + srcB[it] + kb, sB + it * 4096 + w * 1024);
    }
    asm volatile("s_waitcnt vmcnt(0)" ::: "memory");
    __syncthreads();
#pragma unroll
    for (int ks = 0; ks < 2; ++ks) {
      bf16x8 aF[4], bF[4];
      const int g = (lane >> 4) + 4 * ks;
#pragma unroll
      for (int i = 0; i < 4; ++i) {
        const int ra = wm * 64 + i * 16 + (lane & 15);
        aF[i] = *(const bf16x8*)(sA + ra * 128 + ((g ^ (ra & 7)) << 4));
        const int rb = wn * 64 + i * 16 + (lane & 15);
        bF[i] = *(const bf16x8*)(sB + rb * 128 + ((g ^ (rb & 7)) << 4));
      }
#pragma unroll
      for (int mi = 0; mi < 4; ++mi)
#pragma unroll
        for (int ni = 0; ni < 4; ++ni)
          acc[mi][ni] = __builtin_amdgcn_mfma_f32_16x16x32_bf16(
              aF[mi], bF[ni], acc[mi][ni], 0, 0, 0);
    }
    __syncthreads();
  }

  const int cn = lane & 15;
  const int gq = lane >> 4;
#pragma unroll
  for (int mi = 0; mi < 4; ++mi) {
#pragma unroll
    for (int ni = 0; ni < 4; ++ni) {
      const int n  = n0 + wn * 64 + ni * 16 + cn;
      const int mb = m0 + wm * 64 + mi * 16 + 4 * gq;
      const f32x4 v = acc[mi][ni];
      if (MODE == 0) {
        const float bias =
            (n < 1024) ? bias0[n] : ((n < 2048) ? bias1[n - 1024] : bias2[n - 2048]);
        if (n < 2048) {
          bf16* dst = (n < 1024) ? qf : kf;
          const int nn = n & 1023;
#pragma unroll
          for (int j = 0; j < 4; ++j)
            dst[(size_t)(mb + j) * 1024 + nn] = (bf16)(v[j] + bias);
        } else {
          const int nn = n - 2048;
          const int hh = nn >> 6, dd = nn & 63;
          const int bb = mb >> 11, ss = mb & 2047;
          bf16x4 pk;
#pragma unroll
          for (int j = 0; j < 4; ++j) pk[j] = (bf16)(v[j] + bias);
          *(bf16x4*)(vt + ((size_t)((bb * 16 + hh) * 64 + dd) * 2048 + ss)) = pk;
        }
      } else {
        const float bias = bias0[n];
#pragma unroll
        for (int j = 0; j < 4; ++j)
          fout[(size_t)(mb + j) * 1024 + n] = v[j] + bias;
      }
    }
  }
}

// ---------------- flash attention (valid keys: k > q) ----------------
__global__ __launch_bounds__(256, 2) void attn_kernel(
    const bf16* __restrict__ qf, const bf16* __restrict__ kf,
    const bf16* __restrict__ vt, bf16* __restrict__ ao) {
  __shared__ __align__(16) char smem[25600];
  char* sK = smem;          // [64 keys][64 d] swizzled, 8 KB
  char* sV = smem + 8192;   // [64 d][64 keys] swizzled, 8 KB
  char* sP = smem + 16384;  // per-wave P [16][72] bf16

  const int tid  = threadIdx.x;
  const int lane = tid & 63;
  const int w    = tid >> 6;
  const int bid  = blockIdx.x;
  const int jq = bid & 31;
  const int bh = bid >> 5;
  const int b = bh >> 4, h = bh & 15;
  const int q0 = jq * 64;
  const int qbase = q0 + w * 16;

  // Q fragments (pre-scaled by 1/8 -- exact in bf16)
  const char* qrow =
      (const char*)(qf + (size_t)(b * 2048 + qbase + (lane & 15)) * 1024 + h * 64);
  bf16x8 qA[2];
  qA[0] = *(const bf16x8*)(qrow + 16 * (lane >> 4));
  qA[1] = *(const bf16x8*)(qrow + 16 * (lane >> 4) + 64);
#pragma unroll
  for (int ks = 0; ks < 2; ++ks)
#pragma unroll
    for (int i = 0; i < 8; ++i) qA[ks][i] = (bf16)(0.125f * (float)qA[ks][i]);

  const int rs0 = tid >> 3;              // staging row 0..31 (second pass +32)
  const int cg  = (tid & 7) ^ (rs0 & 7); // swizzled chunk (same for row+32)
  const char* kbase = (const char*)kf + ((size_t)(b * 2048) * 1024 + h * 64) * 2;
  const char* vbase = (const char*)vt + (size_t)(bh * 64) * 2048 * 2;

  f32x4 O[4] = {};
  float mrow[4], lrow[4];
#pragma unroll
  for (int j = 0; j < 4; ++j) { mrow[j] = -1e30f; lrow[j] = 0.f; }

  for (int k0 = q0; k0 < 2048; k0 += 64) {
#pragma unroll
    for (int it = 0; it < 2; ++it) {
      const int r = rs0 + it * 32;
      load_lds16(kbase + (size_t)(k0 + r) * 2048 + cg * 16,
                 sK + it * 4096 + w * 1024);
      load_lds16(vbase + (size_t)r * 4096 + (size_t)k0 * 2 + cg * 16,
                 sV + it * 4096 + w * 1024);
    }
    asm volatile("s_waitcnt vmcnt(0)" ::: "memory");
    __syncthreads();

    // QK^T : scores [16 q][64 k]
    f32x4 sc[4] = {};
#pragma unroll
    for (int ks = 0; ks < 2; ++ks) {
      const int g = (lane >> 4) + 4 * ks;
#pragma unroll
      for (int t = 0; t < 4; ++t) {
        const int rk = t * 16 + (lane & 15);
        const bf16x8 kF =
            *(const bf16x8*)(sK + rk * 128 + ((g ^ (rk & 7)) << 4));
        sc[t] = __builtin_amdgcn_mfma_f32_16x16x32_bf16(qA[ks], kF, sc[t], 0, 0, 0);
      }
    }

    if (k0 == q0) {  // diagonal tile: mask k <= q
#pragma unroll
      for (int t = 0; t < 4; ++t)
#pragma unroll
        for (int j = 0; j < 4; ++j) {
          const int kk = k0 + t * 16 + (lane & 15);
          const int qq = qbase + 4 * (lane >> 4) + j;
          if (kk <= qq) sc[t][j] = -1e30f;
        }
    }

    // online softmax (row spread over 16 lanes)
    float tm[4];
#pragma unroll
    for (int j = 0; j < 4; ++j)
      tm[j] = fmaxf(fmaxf(sc[0][j], sc[1][j]), fmaxf(sc[2][j], sc[3][j]));
#pragma unroll
    for (int off = 1; off < 16; off <<= 1)
#pragma unroll
      for (int j = 0; j < 4; ++j) tm[j] = fmaxf(tm[j], __shfl_xor(tm[j], off));

    float alpha[4];
#pragma unroll
    for (int j = 0; j < 4; ++j) {
      const float mn = fmaxf(mrow[j], tm[j]);
      alpha[j] = __expf(mrow[j] - mn);
      mrow[j] = mn;
    }

    float rsum[4] = {0.f, 0.f, 0.f, 0.f};
    bf16* pw = (bf16*)(sP + w * 2304);
#pragma unroll
    for (int t = 0; t < 4; ++t)
#pragma unroll
      for (int j = 0; j < 4; ++j) {
        const float s = sc[t][j];
        const float p = (s > -1e29f) ? __expf(s - mrow[j]) : 0.f;
        const bf16 pb = (bf16)p;
        rsum[j] += (float)pb;
        pw[(4 * (lane >> 4) + j) * 72 + t * 16 + (lane & 15)] = pb;
      }
#pragma unroll
    for (int off = 1; off < 16; off <<= 1)
#pragma unroll
      for (int j = 0; j < 4; ++j) rsum[j] += __shfl_xor(rsum[j], off);
#pragma unroll
    for (int j = 0; j < 4; ++j) lrow[j] = lrow[j] * alpha[j] + rsum[j];
#pragma unroll
    for (int dt = 0; dt < 4; ++dt)
#pragma unroll
      for (int j = 0; j < 4; ++j) O[dt][j] *= alpha[j];

    // PV : O[16 q][64 d] += P * V
#pragma unroll
    for (int ks = 0; ks < 2; ++ks) {
      const bf16x8 pA = *(const bf16x8*)(sP + w * 2304 + (lane & 15) * 144 +
                                         16 * (lane >> 4) + 64 * ks);
      const int g = (lane >> 4) + 4 * ks;
#pragma unroll
      for (int dt = 0; dt < 4; ++dt) {
        const int rv = dt * 16 + (lane & 15);
        const bf16x8 vF =
            *(const bf16x8*)(sV + rv * 128 + ((g ^ (rv & 7)) << 4));
        O[dt] = __builtin_amdgcn_mfma_f32_16x16x32_bf16(pA, vF, O[dt], 0, 0, 0);
      }
    }
    __syncthreads();
  }

  float inv[4];
#pragma unroll
  for (int j = 0; j < 4; ++j) inv[j] = (lrow[j] > 0.f) ? 1.f / lrow[j] : 0.f;
#pragma unroll
  for (int dt = 0; dt < 4; ++dt)
#pragma unroll
    for (int j = 0; j < 4; ++j)
      ao[(size_t)(b * 2048 + qbase + 4 * (lane >> 4) + j) * 1024 + h * 64 +
         dt * 16 + (lane & 15)] = (bf16)(O[dt][j] * inv[j]);
}

// ---------------- last-row fix: ao[q=2047] = mean over s of V ----------------
__global__ __launch_bounds__(256) void vmean_kernel(const bf16* __restrict__ vt,
                                                    bf16* __restrict__ ao) {
  const int tid = threadIdx.x;
  const int lane = tid & 63, w = tid >> 6;
  const int gw = blockIdx.x * 4 + w;  // 0..2047 == bh*64 + d
  const int bh = gw >> 6, d = gw & 63;
  const int b = bh >> 4, h = bh & 15;
  const bf16x8* p = (const bf16x8*)(vt + (size_t)gw * 2048 + lane * 32);
  float s = 0.f;
#pragma unroll
  for (int i = 0; i < 4; ++i) {
    const bf16x8 v = p[i];
#pragma unroll
    for (int j = 0; j < 8; ++j) s += (float)v[j];
  }
  for (int off = 1; off < 64; off <<= 1) s += __shfl_xor(s, off);
  if (lane == 0)
    ao[(size_t)(b * 2048 + 2047) * 1024 + h * 64 + d] = (bf16)(s * (1.f / 2048.f));
}

extern "C" void kernel_launch(void* const* d_in, const int* in_sizes, int n_in,
                              void* d_out, int out_size, void* d_ws,
                              size_t ws_size, hipStream_t stream) {
  const float* x  = (const float*)d_in[0];
  const float* wq = (const float*)d_in[2];
  const float* bq = (const float*)d_in[3];
  const float* wk = (const float*)d_in[4];
  const float* bk = (const float*)d_in[5];
  const float* wv = (const float*)d_in[6];
  const float* bv = (const float*)d_in[7];
  const float* wo = (const float*)d_in[8];
  const float* bo = (const float*)d_in[9];
  float* out = (float*)d_out;

  if (ws_size < (size_t)25165824 * 2) return;  // need ~48 MiB of scratch

  bf16* ws    = (bf16*)d_ws;
  bf16* xb    = ws;                     // [4096][1024]
  bf16* wqkvT = xb + 4194304;           // [3072][1024]
  bf16* woT   = wqkvT + 3145728;        // [1024][1024]
  bf16* qfp   = woT + 1048576;          // [4096][1024] flat
  bf16* kfp   = qfp + 4194304;          // [4096][1024] flat
  bf16* vtp   = kfp + 4194304;          // [b][h][d][s]
  bf16* aop   = vtp + 4194304;          // [4096][1024] flat

  convert_x<<<4096, 256, 0, stream>>>(x, xb);
  transpose_w<<<256, 256, 0, stream>>>(wq, wqkvT);
  transpose_w<<<256, 256, 0, stream>>>(wk, wqkvT + 1048576);
  transpose_w<<<256, 256, 0, stream>>>(wv, wqkvT + 2097152);
  transpose_w<<<256, 256, 0, stream>>>(wo, woT);

  gemm_bt<0><<<32 * 24, 256, 0, stream>>>(xb, wqkvT, bq, bk, bv, qfp, kfp, vtp,
                                          nullptr, 24);
  attn_kernel<<<1024, 256, 0, stream>>>(qfp, kfp, vtp, aop);
  vmean_kernel<<<512, 256, 0, stream>>>(vtp, aop);
  gemm_bt<1><<<32 * 8, 256, 0, stream>>>(aop, woT, bo, nullptr, nullptr, nullptr,
                                         nullptr, nullptr, out, 8);
}

// Round 2
// 139.415 us; speedup vs baseline: 1.3365x; 1.3365x over previous
//
#include <hip/hip_runtime.h>
#include <hip/hip_bf16.h>

// MaskedSelfAttention: B=2, S=2048, D=1024, H=16, depth=64.
// Pipeline: convert/transpose -> fused QKV GEMM (bf16 MFMA) -> flash attn
// (anti-causal mask: valid keys k>q; last row = uniform mean(V)) -> out GEMM.
// R2: attn rework — QBLK=128, paired q-tiles (uniform 34 k-tiles/block),
// double-buffered K/V staging, swapped QK^T (lane-local softmax rows).

using bf16   = __bf16;
using bf16x4 = __attribute__((ext_vector_type(4))) __bf16;
using bf16x8 = __attribute__((ext_vector_type(8))) __bf16;
using f32x4  = __attribute__((ext_vector_type(4))) float;

__device__ __forceinline__ void load_lds16(const void* g, void* l) {
  __builtin_amdgcn_global_load_lds(
      (const __attribute__((address_space(1))) void*)g,
      (__attribute__((address_space(3))) void*)l, 16, 0, 0);
}

// ---------------- convert x (f32 -> bf16) ----------------
__global__ __launch_bounds__(256) void convert_x(const float* __restrict__ x,
                                                 bf16* __restrict__ xb) {
  const int i = (blockIdx.x * 256 + threadIdx.x) * 4;
  const float4 v = *(const float4*)(x + i);
  bf16x4 o;
  o[0] = (bf16)v.x; o[1] = (bf16)v.y; o[2] = (bf16)v.z; o[3] = (bf16)v.w;
  *(bf16x4*)(xb + i) = o;
}

// ---------------- transpose weight [1024][1024] f32 -> [n][k] bf16 ----------------
__global__ __launch_bounds__(256) void transpose_w(const float* __restrict__ w,
                                                   bf16* __restrict__ out) {
  __shared__ float tile[64][65];
  const int t  = threadIdx.x;
  const int n0 = (blockIdx.x & 15) * 64;
  const int k0 = (blockIdx.x >> 4) * 64;
#pragma unroll
  for (int p = 0; p < 4; ++p) {
    const int row = p * 16 + (t >> 4);
    const int c4  = (t & 15) * 4;
    const float4 v = *(const float4*)&w[(size_t)(k0 + row) * 1024 + n0 + c4];
    tile[row][c4 + 0] = v.x; tile[row][c4 + 1] = v.y;
    tile[row][c4 + 2] = v.z; tile[row][c4 + 3] = v.w;
  }
  __syncthreads();
#pragma unroll
  for (int p = 0; p < 4; ++p) {
    const int rn = p * 16 + (t >> 4);
    const int c4 = (t & 15) * 4;
    bf16x4 o;
#pragma unroll
    for (int j = 0; j < 4; ++j) o[j] = (bf16)tile[c4 + j][rn];
    *(bf16x4*)&out[(size_t)(n0 + rn) * 1024 + k0 + c4] = o;
  }
}

// ---------------- GEMM C = A[M][1024] * Bt[N][1024]^T ----------------
template <int MODE>
__global__ __launch_bounds__(256, 2) void gemm_bt(
    const bf16* __restrict__ A, const bf16* __restrict__ Bt,
    const float* __restrict__ bias0, const float* __restrict__ bias1,
    const float* __restrict__ bias2, bf16* __restrict__ qf,
    bf16* __restrict__ kf, bf16* __restrict__ vt, float* __restrict__ fout,
    int Nblocks) {
  __shared__ __align__(16) char smem[32768];
  char* sA = smem;
  char* sB = smem + 16384;
  const int tid = threadIdx.x;
  const int lane = tid & 63;
  const int w = tid >> 6;
  const int wm = w >> 1, wn = w & 1;
  const int bid = blockIdx.x;
  const int m0 = (bid / Nblocks) * 128;
  const int n0 = (bid % Nblocks) * 128;

  const char* Ab = (const char*)A;
  const char* Bb = (const char*)Bt;
  size_t srcA[4], srcB[4];
#pragma unroll
  for (int it = 0; it < 4; ++it) {
    const int o = it * 4096 + tid * 16;
    const int r = o >> 7;
    const int cg = ((o >> 4) & 7) ^ (r & 7);
    srcA[it] = (size_t)(m0 + r) * 2048 + cg * 16;
    srcB[it] = (size_t)(n0 + r) * 2048 + cg * 16;
  }

  f32x4 acc[4][4] = {};

  for (int kt = 0; kt < 16; ++kt) {
    const size_t kb = (size_t)kt * 128;
#pragma unroll
    for (int it = 0; it < 4; ++it) {
      load_lds16(Ab + srcA[it] + kb, sA + it * 4096 + w * 1024);
      load_lds16(Bb + srcB[it] + kb, sB + it * 4096 + w * 1024);
    }
    asm volatile("s_waitcnt vmcnt(0)" ::: "memory");
    __syncthreads();
#pragma unroll
    for (int ks = 0; ks < 2; ++ks) {
      bf16x8 aF[4], bF[4];
      const int g = (lane >> 4) + 4 * ks;
#pragma unroll
      for (int i = 0; i < 4; ++i) {
        const int ra = wm * 64 + i * 16 + (lane & 15);
        aF[i] = *(const bf16x8*)(sA + ra * 128 + ((g ^ (ra & 7)) << 4));
        const int rb = wn * 64 + i * 16 + (lane & 15);
        bF[i] = *(const bf16x8*)(sB + rb * 128 + ((g ^ (rb & 7)) << 4));
      }
#pragma unroll
      for (int mi = 0; mi < 4; ++mi)
#pragma unroll
        for (int ni = 0; ni < 4; ++ni)
          acc[mi][ni] = __builtin_amdgcn_mfma_f32_16x16x32_bf16(
              aF[mi], bF[ni], acc[mi][ni], 0, 0, 0);
    }
    __syncthreads();
  }

  const int cn = lane & 15;
  const int gq = lane >> 4;
#pragma unroll
  for (int mi = 0; mi < 4; ++mi) {
#pragma unroll
    for (int ni = 0; ni < 4; ++ni) {
      const int n  = n0 + wn * 64 + ni * 16 + cn;
      const int mb = m0 + wm * 64 + mi * 16 + 4 * gq;
      const f32x4 v = acc[mi][ni];
      if (MODE == 0) {
        const float bias =
            (n < 1024) ? bias0[n] : ((n < 2048) ? bias1[n - 1024] : bias2[n - 2048]);
        if (n < 2048) {
          bf16* dst = (n < 1024) ? qf : kf;
          const int nn = n & 1023;
#pragma unroll
          for (int j = 0; j < 4; ++j)
            dst[(size_t)(mb + j) * 1024 + nn] = (bf16)(v[j] + bias);
        } else {
          const int nn = n - 2048;
          const int hh = nn >> 6, dd = nn & 63;
          const int bb = mb >> 11, ss = mb & 2047;
          bf16x4 pk;
#pragma unroll
          for (int j = 0; j < 4; ++j) pk[j] = (bf16)(v[j] + bias);
          *(bf16x4*)(vt + ((size_t)((bb * 16 + hh) * 64 + dd) * 2048 + ss)) = pk;
        }
      } else {
        const float bias = bias0[n];
#pragma unroll
        for (int j = 0; j < 4; ++j)
          fout[(size_t)(mb + j) * 1024 + n] = v[j] + bias;
      }
    }
  }
}

// ---------------- flash attention v2 (valid keys: k > q) ----------------
// 256 blocks = 8 pairs x 32 bh. Each block: q-tiles jq=pair and jq=15-pair
// (128 rows each) -> uniform 34 k-tiles of work. 4 waves x 32 q-rows.
// Double-buffered K/V LDS staging; swapped QK^T => softmax rows lane-local.
__global__ __launch_bounds__(256, 2) void attn_kernel(
    const bf16* __restrict__ qf, const bf16* __restrict__ kf,
    const bf16* __restrict__ vt, bf16* __restrict__ ao) {
  // sK[2][8192] | sV[2][8192] | sP[4 waves][32*72*2]
  __shared__ __align__(16) char smem[51200];

  const int tid  = threadIdx.x;
  const int lane = tid & 63;
  const int hi   = lane >> 4;
  const int qlo  = lane & 15;
  const int w    = tid >> 6;
  const int pairIdx = blockIdx.x >> 5;   // 0..7
  const int bh = blockIdx.x & 31;        // same-bh blocks land on same XCD
  const int b = bh >> 4, h = bh & 15;

  const char* kbase = (const char*)kf + ((size_t)b * 2048) * 2048 + h * 128;
  const char* vbase = (const char*)vt + (size_t)bh * 262144;
  const char* qbb   = (const char*)qf + ((size_t)b * 2048) * 2048 + h * 128;

  const int sr  = tid >> 3;              // staging row 0..31 (round 1: +32)
  const int scg = (tid & 7) ^ (sr & 7);  // pre-swizzled source chunk

  char* sPw = smem + 32768 + w * 4608;

  for (int sp = 0; sp < 2; ++sp) {
    const int jq = sp ? (15 - pairIdx) : pairIdx;
    const int q0 = jq * 128;
    const int qb = q0 + w * 32;

    // Q fragments for 2 row-subtiles (pre-scaled by 1/8 -- exact in bf16)
    bf16x8 qA[2][2];
    {
      const char* qrow = qbb + (size_t)(qb + qlo) * 2048;
#pragma unroll
      for (int qt = 0; qt < 2; ++qt)
#pragma unroll
        for (int ks = 0; ks < 2; ++ks) {
          qA[qt][ks] = *(const bf16x8*)(qrow + qt * 32768 + ks * 64 + hi * 16);
#pragma unroll
          for (int i = 0; i < 8; ++i)
            qA[qt][ks][i] = (bf16)(0.125f * (float)qA[qt][ks][i]);
        }
    }

    float m[2] = {-1e30f, -1e30f};
    float l[2] = {0.f, 0.f};
    f32x4 O[2][4] = {};

    const int nt = (2048 - q0) >> 6;

    // prologue: stage tile 0 into buffer 0
    {
      char* dK = smem + w * 1024;
      char* dV = smem + 16384 + w * 1024;
#pragma unroll
      for (int p = 0; p < 2; ++p) {
        load_lds16(kbase + (size_t)(q0 + sr + 32 * p) * 2048 + scg * 16,
                   dK + p * 4096);
        load_lds16(vbase + (size_t)(sr + 32 * p) * 4096 + (size_t)q0 * 2 +
                       scg * 16,
                   dV + p * 4096);
      }
    }
    __syncthreads();

    for (int it = 0; it < nt; ++it) {
      const int cur = it & 1;
      const int k0t = q0 + it * 64;

      // issue next-tile staging first (lands during compute; drained by the
      // barrier at the end of this iteration)
      if (it + 1 < nt) {
        const int kn = k0t + 64;
        char* dK = smem + (cur ^ 1) * 8192 + w * 1024;
        char* dV = smem + 16384 + (cur ^ 1) * 8192 + w * 1024;
#pragma unroll
        for (int p = 0; p < 2; ++p) {
          load_lds16(kbase + (size_t)(kn + sr + 32 * p) * 2048 + scg * 16,
                     dK + p * 4096);
          load_lds16(vbase + (size_t)(sr + 32 * p) * 4096 + (size_t)kn * 2 +
                         scg * 16,
                     dV + p * 4096);
        }
      }
      const char* bK = smem + cur * 8192;
      const char* bV = smem + 16384 + cur * 8192;

      // QK^T swapped: sc[qt][t] has col=q (lane&15), row=k (4*hi+j)
      f32x4 sc[2][4] = {};
#pragma unroll
      for (int ks = 0; ks < 2; ++ks) {
        const int g = hi + 4 * ks;
#pragma unroll
        for (int t = 0; t < 4; ++t) {
          const int rk = t * 16 + qlo;
          const bf16x8 kF =
              *(const bf16x8*)(bK + rk * 128 + ((g ^ (rk & 7)) << 4));
          sc[0][t] = __builtin_amdgcn_mfma_f32_16x16x32_bf16(kF, qA[0][ks],
                                                             sc[0][t], 0, 0, 0);
          sc[1][t] = __builtin_amdgcn_mfma_f32_16x16x32_bf16(kF, qA[1][ks],
                                                             sc[1][t], 0, 0, 0);
        }
      }

      if (k0t < q0 + 128) {  // tiles overlapping the q-range: mask k <= q
#pragma unroll
        for (int qt = 0; qt < 2; ++qt)
#pragma unroll
          for (int t = 0; t < 4; ++t)
#pragma unroll
            for (int j = 0; j < 4; ++j) {
              const int qq = qb + qt * 16 + qlo;
              const int kk = k0t + t * 16 + 4 * hi + j;
              if (kk <= qq) sc[qt][t][j] = -1e30f;
            }
      }

      // online softmax: each lane owns row q=qb+qt*16+qlo (16 k-vals local,
      // full row across hi groups -> 2 shfl rounds)
#pragma unroll
      for (int qt = 0; qt < 2; ++qt) {
        float tm = sc[qt][0][0];
#pragma unroll
        for (int t = 0; t < 4; ++t)
#pragma unroll
          for (int j = 0; j < 4; ++j) tm = fmaxf(tm, sc[qt][t][j]);
        tm = fmaxf(tm, __shfl_xor(tm, 16));
        tm = fmaxf(tm, __shfl_xor(tm, 32));
        const float mn = fmaxf(m[qt], tm);
        const float al = __expf(m[qt] - mn);
        m[qt] = mn;

        float rs = 0.f;
#pragma unroll
        for (int t = 0; t < 4; ++t) {
          bf16x4 pk;
#pragma unroll
          for (int j = 0; j < 4; ++j) {
            const float s = sc[qt][t][j];
            const float p = (s > -1e29f) ? __expf(s - mn) : 0.f;
            pk[j] = (bf16)p;
            rs += (float)pk[j];
          }
          *(bf16x4*)(sPw + (qt * 16 + qlo) * 144 + t * 32 + hi * 8) = pk;
        }
        rs += __shfl_xor(rs, 16);
        rs += __shfl_xor(rs, 32);
        l[qt] = l[qt] * al + rs;

        // rescale O (O rows are 4*hi+j -> gather alpha from lane 4*hi+j)
#pragma unroll
        for (int j = 0; j < 4; ++j) {
          const float alj = __shfl(al, 4 * hi + j);
#pragma unroll
          for (int dt = 0; dt < 4; ++dt) O[qt][dt][j] *= alj;
        }
      }

      // PV: O[q][d] += P[q][k] * V^T[d][k]
#pragma unroll
      for (int ks = 0; ks < 2; ++ks) {
        const int g = hi + 4 * ks;
        const bf16x8 pA0 =
            *(const bf16x8*)(sPw + qlo * 144 + hi * 16 + ks * 64);
        const bf16x8 pA1 =
            *(const bf16x8*)(sPw + (16 + qlo) * 144 + hi * 16 + ks * 64);
#pragma unroll
        for (int dt = 0; dt < 4; ++dt) {
          const int rv = dt * 16 + qlo;
          const bf16x8 vF =
              *(const bf16x8*)(bV + rv * 128 + ((g ^ (rv & 7)) << 4));
          O[0][dt] = __builtin_amdgcn_mfma_f32_16x16x32_bf16(pA0, vF, O[0][dt],
                                                             0, 0, 0);
          O[1][dt] = __builtin_amdgcn_mfma_f32_16x16x32_bf16(pA1, vF, O[1][dt],
                                                             0, 0, 0);
        }
      }
      __syncthreads();
    }

    // epilogue: normalize + write (l lives in lane q; O rows are 4*hi+j)
#pragma unroll
    for (int qt = 0; qt < 2; ++qt) {
      const float linv = (l[qt] > 0.f) ? 1.f / l[qt] : 0.f;
#pragma unroll
      for (int j = 0; j < 4; ++j) {
        const float lj = __shfl(linv, 4 * hi + j);
        const int qg = qb + qt * 16 + 4 * hi + j;
#pragma unroll
        for (int dt = 0; dt < 4; ++dt)
          ao[(size_t)(b * 2048 + qg) * 1024 + h * 64 + dt * 16 + qlo] =
              (bf16)(O[qt][dt][j] * lj);
      }
    }
  }
}

// ---------------- last-row fix: ao[q=2047] = mean over s of V ----------------
__global__ __launch_bounds__(256) void vmean_kernel(const bf16* __restrict__ vt,
                                                    bf16* __restrict__ ao) {
  const int tid = threadIdx.x;
  const int lane = tid & 63, w = tid >> 6;
  const int gw = blockIdx.x * 4 + w;  // 0..2047 == bh*64 + d
  const int bh = gw >> 6, d = gw & 63;
  const int b = bh >> 4, h = bh & 15;
  const bf16x8* p = (const bf16x8*)(vt + (size_t)gw * 2048 + lane * 32);
  float s = 0.f;
#pragma unroll
  for (int i = 0; i < 4; ++i) {
    const bf16x8 v = p[i];
#pragma unroll
    for (int j = 0; j < 8; ++j) s += (float)v[j];
  }
  for (int off = 1; off < 64; off <<= 1) s += __shfl_xor(s, off);
  if (lane == 0)
    ao[(size_t)(b * 2048 + 2047) * 1024 + h * 64 + d] = (bf16)(s * (1.f / 2048.f));
}

extern "C" void kernel_launch(void* const* d_in, const int* in_sizes, int n_in,
                              void* d_out, int out_size, void* d_ws,
                              size_t ws_size, hipStream_t stream) {
  const float* x  = (const float*)d_in[0];
  const float* wq = (const float*)d_in[2];
  const float* bq = (const float*)d_in[3];
  const float* wk = (const float*)d_in[4];
  const float* bk = (const float*)d_in[5];
  const float* wv = (const float*)d_in[6];
  const float* bv = (const float*)d_in[7];
  const float* wo = (const float*)d_in[8];
  const float* bo = (const float*)d_in[9];
  float* out = (float*)d_out;

  if (ws_size < (size_t)25165824 * 2) return;  // need ~48 MiB of scratch

  bf16* ws    = (bf16*)d_ws;
  bf16* xb    = ws;                     // [4096][1024]
  bf16* wqkvT = xb + 4194304;           // [3072][1024]
  bf16* woT   = wqkvT + 3145728;        // [1024][1024]
  bf16* qfp   = woT + 1048576;          // [4096][1024] flat
  bf16* kfp   = qfp + 4194304;          // [4096][1024] flat
  bf16* vtp   = kfp + 4194304;          // [b][h][d][s]
  bf16* aop   = vtp + 4194304;          // [4096][1024] flat

  convert_x<<<4096, 256, 0, stream>>>(x, xb);
  transpose_w<<<256, 256, 0, stream>>>(wq, wqkvT);
  transpose_w<<<256, 256, 0, stream>>>(wk, wqkvT + 1048576);
  transpose_w<<<256, 256, 0, stream>>>(wv, wqkvT + 2097152);
  transpose_w<<<256, 256, 0, stream>>>(wo, woT);

  gemm_bt<0><<<32 * 24, 256, 0, stream>>>(xb, wqkvT, bq, bk, bv, qfp, kfp, vtp,
                                          nullptr, 24);
  attn_kernel<<<256, 256, 0, stream>>>(qfp, kfp, vtp, aop);
  vmean_kernel<<<512, 256, 0, stream>>>(vtp, aop);
  gemm_bt<1><<<32 * 8, 256, 0, stream>>>(aop, woT, bo, nullptr, nullptr, nullptr,
                                         nullptr, nullptr, out, 8);
}

// Round 3
// 110.916 us; speedup vs baseline: 1.6800x; 1.2569x over previous
//
#include <hip/hip_runtime.h>
#include <hip/hip_bf16.h>

// MaskedSelfAttention: B=2, S=2048, D=1024, H=16, depth=64.
// prep (convert+transpose) -> fused QKV GEMM -> flash attn (anti-causal:
// valid k>q; q=2047 row = mean(V) via vmean) -> out GEMM.
// R3: attn occupancy 2 blocks/CU (64-row q-tiles, 512 blocks), T13 defer-max,
// l-row-sum via ones-MFMA (kills shfl/bpermute on the critical path).

using bf16   = __bf16;
using bf16x4 = __attribute__((ext_vector_type(4))) __bf16;
using bf16x8 = __attribute__((ext_vector_type(8))) __bf16;
using f32x4  = __attribute__((ext_vector_type(4))) float;

__device__ __forceinline__ void load_lds16(const void* g, void* l) {
  __builtin_amdgcn_global_load_lds(
      (const __attribute__((address_space(1))) void*)g,
      (__attribute__((address_space(3))) void*)l, 16, 0, 0);
}

// ---------------- prep: convert x + transpose 4 weights ----------------
__global__ __launch_bounds__(256) void prep_kernel(
    const float* __restrict__ x, bf16* __restrict__ xb,
    const float* __restrict__ wq, const float* __restrict__ wk,
    const float* __restrict__ wv, const float* __restrict__ wo,
    bf16* __restrict__ wT) {
  const int t = threadIdx.x;
  int bid = blockIdx.x;
  if (bid < 4096) {  // convert x: f32 -> bf16
    const int i = (bid * 256 + t) * 4;
    const float4 v = *(const float4*)(x + i);
    bf16x4 o;
    o[0] = (bf16)v.x; o[1] = (bf16)v.y; o[2] = (bf16)v.z; o[3] = (bf16)v.w;
    *(bf16x4*)(xb + i) = o;
    return;
  }
  bid -= 4096;
  const int sel = bid >> 8;  // 0..3 : wq wk wv wo
  const float* w = (sel == 0) ? wq : (sel == 1) ? wk : (sel == 2) ? wv : wo;
  bf16* out = wT + (size_t)sel * 1048576;
  __shared__ float tile[64][65];
  const int n0 = (bid & 15) * 64;
  const int k0 = ((bid >> 4) & 15) * 64;
#pragma unroll
  for (int p = 0; p < 4; ++p) {
    const int row = p * 16 + (t >> 4);
    const int c4  = (t & 15) * 4;
    const float4 v = *(const float4*)&w[(size_t)(k0 + row) * 1024 + n0 + c4];
    tile[row][c4 + 0] = v.x; tile[row][c4 + 1] = v.y;
    tile[row][c4 + 2] = v.z; tile[row][c4 + 3] = v.w;
  }
  __syncthreads();
#pragma unroll
  for (int p = 0; p < 4; ++p) {
    const int rn = p * 16 + (t >> 4);
    const int c4 = (t & 15) * 4;
    bf16x4 o;
#pragma unroll
    for (int j = 0; j < 4; ++j) o[j] = (bf16)tile[c4 + j][rn];
    *(bf16x4*)&out[(size_t)(n0 + rn) * 1024 + k0 + c4] = o;
  }
}

// ---------------- GEMM C = A[M][1024] * Bt[N][1024]^T ----------------
template <int MODE>
__global__ __launch_bounds__(256, 2) void gemm_bt(
    const bf16* __restrict__ A, const bf16* __restrict__ Bt,
    const float* __restrict__ bias0, const float* __restrict__ bias1,
    const float* __restrict__ bias2, bf16* __restrict__ qf,
    bf16* __restrict__ kf, bf16* __restrict__ vt, float* __restrict__ fout,
    int Nblocks) {
  __shared__ __align__(16) char smem[32768];
  char* sA = smem;
  char* sB = smem + 16384;
  const int tid = threadIdx.x;
  const int lane = tid & 63;
  const int w = tid >> 6;
  const int wm = w >> 1, wn = w & 1;
  const int bid = blockIdx.x;
  const int m0 = (bid / Nblocks) * 128;
  const int n0 = (bid % Nblocks) * 128;

  const char* Ab = (const char*)A;
  const char* Bb = (const char*)Bt;
  size_t srcA[4], srcB[4];
#pragma unroll
  for (int it = 0; it < 4; ++it) {
    const int o = it * 4096 + tid * 16;
    const int r = o >> 7;
    const int cg = ((o >> 4) & 7) ^ (r & 7);
    srcA[it] = (size_t)(m0 + r) * 2048 + cg * 16;
    srcB[it] = (size_t)(n0 + r) * 2048 + cg * 16;
  }

  f32x4 acc[4][4] = {};

  for (int kt = 0; kt < 16; ++kt) {
    const size_t kb = (size_t)kt * 128;
#pragma unroll
    for (int it = 0; it < 4; ++it) {
      load_lds16(Ab + srcA[it] + kb, sA + it * 4096 + w * 1024);
      load_lds16(Bb + srcB[it] + kb, sB + it * 4096 + w * 1024);
    }
    asm volatile("s_waitcnt vmcnt(0)" ::: "memory");
    __syncthreads();
#pragma unroll
    for (int ks = 0; ks < 2; ++ks) {
      bf16x8 aF[4], bF[4];
      const int g = (lane >> 4) + 4 * ks;
#pragma unroll
      for (int i = 0; i < 4; ++i) {
        const int ra = wm * 64 + i * 16 + (lane & 15);
        aF[i] = *(const bf16x8*)(sA + ra * 128 + ((g ^ (ra & 7)) << 4));
        const int rb = wn * 64 + i * 16 + (lane & 15);
        bF[i] = *(const bf16x8*)(sB + rb * 128 + ((g ^ (rb & 7)) << 4));
      }
#pragma unroll
      for (int mi = 0; mi < 4; ++mi)
#pragma unroll
        for (int ni = 0; ni < 4; ++ni)
          acc[mi][ni] = __builtin_amdgcn_mfma_f32_16x16x32_bf16(
              aF[mi], bF[ni], acc[mi][ni], 0, 0, 0);
    }
    __syncthreads();
  }

  const int cn = lane & 15;
  const int gq = lane >> 4;
#pragma unroll
  for (int mi = 0; mi < 4; ++mi) {
#pragma unroll
    for (int ni = 0; ni < 4; ++ni) {
      const int n  = n0 + wn * 64 + ni * 16 + cn;
      const int mb = m0 + wm * 64 + mi * 16 + 4 * gq;
      const f32x4 v = acc[mi][ni];
      if (MODE == 0) {
        const float bias =
            (n < 1024) ? bias0[n] : ((n < 2048) ? bias1[n - 1024] : bias2[n - 2048]);
        if (n < 2048) {
          bf16* dst = (n < 1024) ? qf : kf;
          const int nn = n & 1023;
#pragma unroll
          for (int j = 0; j < 4; ++j)
            dst[(size_t)(mb + j) * 1024 + nn] = (bf16)(v[j] + bias);
        } else {
          const int nn = n - 2048;
          const int hh = nn >> 6, dd = nn & 63;
          const int bb = mb >> 11, ss = mb & 2047;
          bf16x4 pk;
#pragma unroll
          for (int j = 0; j < 4; ++j) pk[j] = (bf16)(v[j] + bias);
          *(bf16x4*)(vt + ((size_t)((bb * 16 + hh) * 64 + dd) * 2048 + ss)) = pk;
        }
      } else {
        const float bias = bias0[n];
#pragma unroll
        for (int j = 0; j < 4; ++j)
          fout[(size_t)(mb + j) * 1024 + n] = v[j] + bias;
      }
    }
  }
}

// ---------------- flash attention v3 (valid keys: k > q) ----------------
// 512 blocks = 16 pairs x 32 bh; q-tiles (jq, 31-jq) of 64 rows -> uniform
// 33 k-tiles/block. 4 waves x 16 q-rows; 2 blocks/CU for latency hiding.
// Swapped QK^T (softmax col-lane-local), defer-max (T13), l via ones-MFMA.
__global__ __launch_bounds__(256, 2) void attn_kernel(
    const bf16* __restrict__ qf, const bf16* __restrict__ kf,
    const bf16* __restrict__ vt, bf16* __restrict__ ao) {
  // sK[2][8192] | sV[2][8192] | sP[4 waves][16*144]
  __shared__ __align__(16) char smem[41984];

  const int tid  = threadIdx.x;
  const int lane = tid & 63;
  const int hi   = lane >> 4;
  const int qlo  = lane & 15;
  const int w    = tid >> 6;
  const int pairIdx = blockIdx.x >> 5;   // 0..15
  const int bh = blockIdx.x & 31;        // same-bh blocks share an XCD's L2
  const int b = bh >> 4, h = bh & 15;

  const char* kbase = (const char*)kf + ((size_t)b * 2048) * 2048 + h * 128;
  const char* vbase = (const char*)vt + (size_t)bh * 262144;
  const char* qbb   = (const char*)qf + ((size_t)b * 2048) * 2048 + h * 128;

  const int sr  = tid >> 3;              // staging row 0..31 (round 1: +32)
  const int scg = (tid & 7) ^ (sr & 7);  // pre-swizzled source chunk

  char* sPw = smem + 32768 + w * 2304;

  bf16x8 onesB;
#pragma unroll
  for (int i = 0; i < 8; ++i) onesB[i] = (bf16)1.0f;

  for (int sp = 0; sp < 2; ++sp) {
    const int jq = sp ? (31 - pairIdx) : pairIdx;
    const int q0 = jq * 64;
    const int qb = q0 + w * 16;

    // Q fragments (pre-scaled by 1/8 -- exact in bf16)
    bf16x8 qA[2];
    {
      const char* qrow = qbb + (size_t)(qb + qlo) * 2048;
#pragma unroll
      for (int ks = 0; ks < 2; ++ks) {
        qA[ks] = *(const bf16x8*)(qrow + ks * 64 + hi * 16);
#pragma unroll
        for (int i = 0; i < 8; ++i)
          qA[ks][i] = (bf16)(0.125f * (float)qA[ks][i]);
      }
    }

    float m = -1e30f;
    f32x4 lacc = {};
    f32x4 O[4] = {};

    const int nt = (2048 - q0) >> 6;

    // prologue: stage tile 0 into buffer 0
    {
      char* dK = smem + w * 1024;
      char* dV = smem + 16384 + w * 1024;
#pragma unroll
      for (int p = 0; p < 2; ++p) {
        load_lds16(kbase + (size_t)(q0 + sr + 32 * p) * 2048 + scg * 16,
                   dK + p * 4096);
        load_lds16(vbase + (size_t)(sr + 32 * p) * 4096 + (size_t)q0 * 2 +
                       scg * 16,
                   dV + p * 4096);
      }
    }
    __syncthreads();

    for (int it = 0; it < nt; ++it) {
      const int cur = it & 1;

      // issue next-tile staging (drains at this iteration's closing barrier)
      if (it + 1 < nt) {
        const int kn = q0 + it * 64 + 64;
        char* dK = smem + (cur ^ 1) * 8192 + w * 1024;
        char* dV = smem + 16384 + (cur ^ 1) * 8192 + w * 1024;
#pragma unroll
        for (int p = 0; p < 2; ++p) {
          load_lds16(kbase + (size_t)(kn + sr + 32 * p) * 2048 + scg * 16,
                     dK + p * 4096);
          load_lds16(vbase + (size_t)(sr + 32 * p) * 4096 + (size_t)kn * 2 +
                         scg * 16,
                     dV + p * 4096);
        }
      }
      const char* bK = smem + cur * 8192;
      const char* bV = smem + 16384 + cur * 8192;

      // QK^T swapped: sc[t] rows = k (4*hi+j within 16-tile t), col = q (qlo)
      f32x4 sc[4] = {};
#pragma unroll
      for (int ks = 0; ks < 2; ++ks) {
        const int g = hi + 4 * ks;
#pragma unroll
        for (int t = 0; t < 4; ++t) {
          const int rk = t * 16 + qlo;
          const bf16x8 kF =
              *(const bf16x8*)(bK + rk * 128 + ((g ^ (rk & 7)) << 4));
          sc[t] = __builtin_amdgcn_mfma_f32_16x16x32_bf16(kF, qA[ks], sc[t],
                                                          0, 0, 0);
        }
      }

      if (it == 0) {  // diagonal tile: mask k <= q
#pragma unroll
        for (int t = 0; t < 4; ++t)
#pragma unroll
          for (int j = 0; j < 4; ++j) {
            const int kk = q0 + t * 16 + 4 * hi + j;
            const int qq = qb + qlo;
            if (kk <= qq) sc[t][j] = -1e30f;
          }
      }

      // tile max (row q = qlo is lane-local over 16 vals + 2 shfl)
      float tm = sc[0][0];
#pragma unroll
      for (int t = 0; t < 4; ++t)
#pragma unroll
        for (int j = 0; j < 4; ++j) tm = fmaxf(tm, sc[t][j]);
      tm = fmaxf(tm, __shfl_xor(tm, 16));
      tm = fmaxf(tm, __shfl_xor(tm, 32));

      // T13 defer-max: rescale only when some row's max grew by > 8
      if (!__all(tm - m <= 8.0f)) {
        const float mn = fmaxf(m, tm);
        const float al = __expf(m - mn);
        m = mn;
#pragma unroll
        for (int j = 0; j < 4; ++j) {
          const float alj = __shfl(al, 4 * hi + j);
          lacc[j] *= alj;
#pragma unroll
          for (int dt = 0; dt < 4; ++dt) O[dt][j] *= alj;
        }
      }

      // P = exp(s - m) -> bf16, store [q:16][k:64] rows (stride 144 B)
      bf16* pw = (bf16*)(sPw + qlo * 144);
#pragma unroll
      for (int t = 0; t < 4; ++t) {
        bf16x4 pk;
#pragma unroll
        for (int j = 0; j < 4; ++j) pk[j] = (bf16)__expf(sc[t][j] - m);
        *(bf16x4*)(pw + t * 16 + hi * 4) = pk;
      }

      // PV: O[q][d] += P*V ; l rows via ones-MFMA (reuses pA)
#pragma unroll
      for (int ks = 0; ks < 2; ++ks) {
        const bf16x8 pA =
            *(const bf16x8*)(sPw + qlo * 144 + hi * 16 + ks * 64);
        lacc = __builtin_amdgcn_mfma_f32_16x16x32_bf16(pA, onesB, lacc, 0, 0, 0);
        const int g = hi + 4 * ks;
#pragma unroll
        for (int dt = 0; dt < 4; ++dt) {
          const int rv = dt * 16 + qlo;
          const bf16x8 vF =
              *(const bf16x8*)(bV + rv * 128 + ((g ^ (rv & 7)) << 4));
          O[dt] = __builtin_amdgcn_mfma_f32_16x16x32_bf16(pA, vF, O[dt],
                                                          0, 0, 0);
        }
      }
      __syncthreads();
    }

    // epilogue: all state is row-local now (O rows 4*hi+j, lacc[j] same rows)
#pragma unroll
    for (int j = 0; j < 4; ++j) {
      const float linv = (lacc[j] > 0.f) ? 1.f / lacc[j] : 0.f;
      const int qg = qb + 4 * hi + j;
#pragma unroll
      for (int dt = 0; dt < 4; ++dt)
        ao[(size_t)(b * 2048 + qg) * 1024 + h * 64 + dt * 16 + qlo] =
            (bf16)(O[dt][j] * linv);
    }
  }
}

// ---------------- last-row fix: ao[q=2047] = mean over s of V ----------------
__global__ __launch_bounds__(256) void vmean_kernel(const bf16* __restrict__ vt,
                                                    bf16* __restrict__ ao) {
  const int tid = threadIdx.x;
  const int lane = tid & 63, w = tid >> 6;
  const int gw = blockIdx.x * 4 + w;  // 0..2047 == bh*64 + d
  const int bh = gw >> 6, d = gw & 63;
  const int b = bh >> 4, h = bh & 15;
  const bf16x8* p = (const bf16x8*)(vt + (size_t)gw * 2048 + lane * 32);
  float s = 0.f;
#pragma unroll
  for (int i = 0; i < 4; ++i) {
    const bf16x8 v = p[i];
#pragma unroll
    for (int j = 0; j < 8; ++j) s += (float)v[j];
  }
  for (int off = 1; off < 64; off <<= 1) s += __shfl_xor(s, off);
  if (lane == 0)
    ao[(size_t)(b * 2048 + 2047) * 1024 + h * 64 + d] = (bf16)(s * (1.f / 2048.f));
}

extern "C" void kernel_launch(void* const* d_in, const int* in_sizes, int n_in,
                              void* d_out, int out_size, void* d_ws,
                              size_t ws_size, hipStream_t stream) {
  const float* x  = (const float*)d_in[0];
  const float* wq = (const float*)d_in[2];
  const float* bq = (const float*)d_in[3];
  const float* wk = (const float*)d_in[4];
  const float* bk = (const float*)d_in[5];
  const float* wv = (const float*)d_in[6];
  const float* bv = (const float*)d_in[7];
  const float* wo = (const float*)d_in[8];
  const float* bo = (const float*)d_in[9];
  float* out = (float*)d_out;

  if (ws_size < (size_t)25165824 * 2) return;  // need ~48 MiB of scratch

  bf16* ws    = (bf16*)d_ws;
  bf16* xb    = ws;                     // [4096][1024]
  bf16* wqkvT = xb + 4194304;           // [3072][1024]
  bf16* woT   = wqkvT + 3145728;        // [1024][1024]  (contiguous after)
  bf16* qfp   = woT + 1048576;          // [4096][1024] flat
  bf16* kfp   = qfp + 4194304;          // [4096][1024] flat
  bf16* vtp   = kfp + 4194304;          // [b][h][d][s]
  bf16* aop   = vtp + 4194304;          // [4096][1024] flat

  prep_kernel<<<5120, 256, 0, stream>>>(x, xb, wq, wk, wv, wo, wqkvT);

  gemm_bt<0><<<32 * 24, 256, 0, stream>>>(xb, wqkvT, bq, bk, bv, qfp, kfp, vtp,
                                          nullptr, 24);
  attn_kernel<<<512, 256, 0, stream>>>(qfp, kfp, vtp, aop);
  vmean_kernel<<<512, 256, 0, stream>>>(vtp, aop);
  gemm_bt<1><<<32 * 8, 256, 0, stream>>>(aop, woT, bo, nullptr, nullptr, nullptr,
                                         nullptr, nullptr, out, 8);
}